// Round 1
// baseline (186.047 us; speedup 1.0000x reference)
//
#include <hip/hip_runtime.h>
#include <hip/hip_bf16.h>

#define N_ROWS    4096
#define N_CLASSES 32000
#define D_FEAT    1024

typedef __attribute__((ext_vector_type(8))) short bf16x8;
typedef __attribute__((ext_vector_type(4))) short bf16x4;
typedef __attribute__((ext_vector_type(4))) float f32x4;

__device__ __forceinline__ short f2bf(float f) {
    union { float f; unsigned u; } x; x.f = f;
    unsigned r = x.u + 0x7FFFu + ((x.u >> 16) & 1u);   // RNE
    return (short)(r >> 16);
}

// ---------------- norms + accumulator zero-init ----------------
__global__ __launch_bounds__(256) void norm_kernel(const float* __restrict__ feat,
                                                   float* __restrict__ norms,
                                                   float* __restrict__ accums) {
    int row = blockIdx.x;
    int t = threadIdx.x;
    const float4* rp = (const float4*)(feat + (size_t)row * D_FEAT);
    float4 v = rp[t];                       // 256 threads * 4 floats = 1024
    float ss = v.x*v.x + v.y*v.y + v.z*v.z + v.w*v.w;
    #pragma unroll
    for (int off = 1; off < 64; off <<= 1) ss += __shfl_xor(ss, off);
    __shared__ float red[4];
    int wid = t >> 6, lane = t & 63;
    if (lane == 0) red[wid] = ss;
    __syncthreads();
    if (t == 0) {
        float total = red[0] + red[1] + red[2] + red[3];
        norms[row] = sqrtf(total);
        if (row == 0) { accums[0] = 0.f; accums[1] = 0.f; }
    }
}

// ---------------- cross entropy: one block per row ----------------
__global__ __launch_bounds__(256) void ce_kernel(const float* __restrict__ logits,
                                                 const int* __restrict__ labels,
                                                 float* __restrict__ accums) {
    int row = blockIdx.x;
    const float* rp = logits + (size_t)row * N_CLASSES;
    const float4* rp4 = (const float4*)rp;
    int t = threadIdx.x;
    float m = -3.4e38f, s = 0.f;
    for (int j = t; j < N_CLASSES / 4; j += 256) {
        float4 v = rp4[j];
        float vm = fmaxf(fmaxf(v.x, v.y), fmaxf(v.z, v.w));
        if (vm > m) { s *= __expf(m - vm); m = vm; }
        s += __expf(v.x - m) + __expf(v.y - m) + __expf(v.z - m) + __expf(v.w - m);
    }
    // wave-level (m,s) combine
    #pragma unroll
    for (int off = 1; off < 64; off <<= 1) {
        float om = __shfl_xor(m, off);
        float os = __shfl_xor(s, off);
        float M = fmaxf(m, om);
        s = s * __expf(m - M) + os * __expf(om - M);
        m = M;
    }
    __shared__ float sm[4], ssh[4];
    int wid = t >> 6, lane = t & 63;
    if (lane == 0) { sm[wid] = m; ssh[wid] = s; }
    __syncthreads();
    if (t == 0) {
        float M = fmaxf(fmaxf(sm[0], sm[1]), fmaxf(sm[2], sm[3]));
        float S = ssh[0] * __expf(sm[0] - M) + ssh[1] * __expf(sm[1] - M)
                + ssh[2] * __expf(sm[2] - M) + ssh[3] * __expf(sm[3] - M);
        float lse = M + logf(S);
        float ce = lse - rp[labels[row]];
        atomicAdd(accums, ce);
    }
}

// ---------------- gram + hinge: lower-triangle 128x128 blocks ----------------
#define BK 32
#define LDSS 40   // padded LDS row stride in bf16 elements (32 + 8)

__global__ __launch_bounds__(256) void gram_hinge_kernel(const float* __restrict__ feat,
                                                         const float* __restrict__ norms,
                                                         float* __restrict__ accums) {
    // decode lower-triangle block (bi >= bj)
    int t = blockIdx.x;
    int bi = (int)((sqrtf(8.f * (float)t + 1.f) - 1.f) * 0.5f);
    while ((bi + 1) * (bi + 2) / 2 <= t) ++bi;
    while (bi * (bi + 1) / 2 > t) --bi;
    int bj = t - bi * (bi + 1) / 2;

    __shared__ short As[128 * LDSS];
    __shared__ short Bs[128 * LDSS];
    __shared__ float hred[4];

    int tid = threadIdx.x;
    int lane = tid & 63;
    int wid = tid >> 6;
    int wr = wid >> 1, wc = wid & 1;       // 2x2 waves, each 64x64

    f32x4 acc[4][4] = {};

    const int rowA = bi * 128, rowB = bj * 128;
    int fr = lane & 15, ko = (lane >> 4) * 8;

    for (int k0 = 0; k0 < D_FEAT; k0 += BK) {
        // stage: tile viewed as [128][8] float4; 4 float4 per thread per tile
        #pragma unroll
        for (int q = 0; q < 4; ++q) {
            int idx = q * 256 + tid;               // 0..1023
            int r = idx >> 3, c4 = idx & 7;
            float4 va = *(const float4*)(feat + (size_t)(rowA + r) * D_FEAT + k0 + c4 * 4);
            float4 vb = *(const float4*)(feat + (size_t)(rowB + r) * D_FEAT + k0 + c4 * 4);
            bf16x4 ba, bb;
            ba[0] = f2bf(va.x); ba[1] = f2bf(va.y); ba[2] = f2bf(va.z); ba[3] = f2bf(va.w);
            bb[0] = f2bf(vb.x); bb[1] = f2bf(vb.y); bb[2] = f2bf(vb.z); bb[3] = f2bf(vb.w);
            *(bf16x4*)(&As[r * LDSS + c4 * 4]) = ba;
            *(bf16x4*)(&Bs[r * LDSS + c4 * 4]) = bb;
        }
        __syncthreads();

        bf16x8 afr[4], bfr[4];
        #pragma unroll
        for (int mi = 0; mi < 4; ++mi)
            afr[mi] = *(const bf16x8*)(&As[(wr * 64 + mi * 16 + fr) * LDSS + ko]);
        #pragma unroll
        for (int ni = 0; ni < 4; ++ni)
            bfr[ni] = *(const bf16x8*)(&Bs[(wc * 64 + ni * 16 + fr) * LDSS + ko]);

        #pragma unroll
        for (int mi = 0; mi < 4; ++mi)
            #pragma unroll
            for (int ni = 0; ni < 4; ++ni)
                acc[mi][ni] = __builtin_amdgcn_mfma_f32_16x16x32_bf16(afr[mi], bfr[ni], acc[mi][ni], 0, 0, 0);
        __syncthreads();
    }

    // epilogue: hinge accumulate over row>col elements only (strict lower triangle)
    float partial = 0.f;
    int rq = lane >> 4;
    #pragma unroll
    for (int mi = 0; mi < 4; ++mi) {
        #pragma unroll
        for (int ni = 0; ni < 4; ++ni) {
            #pragma unroll
            for (int r = 0; r < 4; ++r) {
                int grow = rowA + wr * 64 + mi * 16 + rq * 4 + r;
                int gcol = rowB + wc * 64 + ni * 16 + fr;
                if (grow > gcol) {
                    float c = acc[mi][ni][r] / fmaxf(norms[grow] * norms[gcol], 1e-8f);
                    partial += fmaxf(c, 0.f);
                }
            }
        }
    }
    #pragma unroll
    for (int off = 1; off < 64; off <<= 1) partial += __shfl_xor(partial, off);
    if (lane == 0) hred[wid] = partial;
    __syncthreads();
    if (tid == 0) atomicAdd(accums + 1, hred[0] + hred[1] + hred[2] + hred[3]);
}

// ---------------- finalize ----------------
__global__ void finalize_kernel(const float* __restrict__ accums, float* __restrict__ out) {
    float ce = accums[0] / (float)N_ROWS;
    // accums[1] = sum over strict lower triangle; ordered pairs = 2x
    float contrastive = 2.f * accums[1] / ((float)N_ROWS * (float)(N_ROWS - 1));
    out[0] = ce + 0.1f * contrastive;
}

extern "C" void kernel_launch(void* const* d_in, const int* in_sizes, int n_in,
                              void* d_out, int out_size, void* d_ws, size_t ws_size,
                              hipStream_t stream) {
    const float* logits = (const float*)d_in[0];
    const int*   labels = (const int*)d_in[1];
    const float* feat   = (const float*)d_in[2];
    float* out = (float*)d_out;

    float* accums = (float*)d_ws;            // [0]=ce sum, [1]=hinge sum
    float* norms  = (float*)d_ws + 64;       // 4096 floats at byte offset 256

    norm_kernel<<<N_ROWS, 256, 0, stream>>>(feat, norms, accums);
    ce_kernel<<<N_ROWS, 256, 0, stream>>>(logits, labels, accums);

    int nblocks = (N_ROWS / 128) * (N_ROWS / 128 + 1) / 2;   // 528
    gram_hinge_kernel<<<nblocks, 256, 0, stream>>>(feat, norms, accums);

    finalize_kernel<<<1, 1, 0, stream>>>(accums, out);
}

// Round 2
// 172.446 us; speedup vs baseline: 1.0789x; 1.0789x over previous
//
#include <hip/hip_runtime.h>
#include <hip/hip_bf16.h>

#define N_ROWS    4096
#define N_CLASSES 32000
#define D_FEAT    1024
#define NBLK_GRAM 528        // 32*33/2 lower-triangle 128x128 blocks

typedef __attribute__((ext_vector_type(8))) short bf16x8;
typedef __attribute__((ext_vector_type(4))) short bf16x4;
typedef __attribute__((ext_vector_type(4))) float f32x4;

__device__ __forceinline__ short f2bf(float f) {
    union { float f; unsigned u; } x; x.f = f;
    unsigned r = x.u + 0x7FFFu + ((x.u >> 16) & 1u);   // RNE
    return (short)(r >> 16);
}

// async global->LDS, 16B per lane. LDS dest must be wave-uniform base;
// HW adds lane*16. (CK-style uintptr addrspace cast.)
__device__ __forceinline__ void gload_lds16(const void* g, void* l) {
    auto gp = reinterpret_cast<const __attribute__((address_space(1))) char*>(
        reinterpret_cast<uintptr_t>(g));
    auto lp = reinterpret_cast<__attribute__((address_space(3))) char*>(
        reinterpret_cast<uintptr_t>(l));
    __builtin_amdgcn_global_load_lds(gp, lp, 16, 0, 0);
}

// ---------------- prep: norms + f32->bf16 convert + accum zero ----------------
__global__ __launch_bounds__(256) void prep_kernel(const float* __restrict__ feat,
                                                   short* __restrict__ featb,
                                                   float* __restrict__ norms,
                                                   float* __restrict__ accums) {
    int row = blockIdx.x;
    int t = threadIdx.x;
    const float4* rp = (const float4*)(feat + (size_t)row * D_FEAT);
    float4 v = rp[t];                       // 256 threads * 4 floats = 1024
    float ss = v.x*v.x + v.y*v.y + v.z*v.z + v.w*v.w;
    bf16x4 b;
    b[0] = f2bf(v.x); b[1] = f2bf(v.y); b[2] = f2bf(v.z); b[3] = f2bf(v.w);
    *(bf16x4*)(featb + (size_t)row * D_FEAT + t * 4) = b;
    #pragma unroll
    for (int off = 1; off < 64; off <<= 1) ss += __shfl_xor(ss, off);
    __shared__ float red[4];
    int wid = t >> 6, lane = t & 63;
    if (lane == 0) red[wid] = ss;
    __syncthreads();
    if (t == 0) {
        norms[row] = sqrtf(red[0] + red[1] + red[2] + red[3]);
        if (row == 0) { accums[0] = 0.f; accums[1] = 0.f; }
    }
}

// ---------------- fused: gram (blocks 0..527) + CE (blocks 528..4623) --------
__global__ __launch_bounds__(256) void fused_kernel(const float* __restrict__ logits,
                                                    const int* __restrict__ labels,
                                                    const short* __restrict__ featb,
                                                    const float* __restrict__ norms,
                                                    float* __restrict__ accums) {
    __shared__ short As[128 * 32];
    __shared__ short Bs[128 * 32];
    __shared__ float red[8];

    int tid = threadIdx.x;
    int lane = tid & 63;
    int wid = tid >> 6;

    if (blockIdx.x < NBLK_GRAM) {
        // ---- gram + hinge: lower-triangle 128x128 block ----
        int t = blockIdx.x;
        int bi = (int)((sqrtf(8.f * (float)t + 1.f) - 1.f) * 0.5f);
        while ((bi + 1) * (bi + 2) / 2 <= t) ++bi;
        while (bi * (bi + 1) / 2 > t) --bi;
        int bj = t - bi * (bi + 1) / 2;

        int wr = wid >> 1, wc = wid & 1;      // 2x2 waves, each 64x64
        int fr = lane & 15, q = lane >> 4;    // frag row, k-chunk
        int sw = (q ^ (fr & 3)) * 8;          // swizzled chunk position (shorts)

        f32x4 acc[4][4] = {};
        const int rowA = bi * 128, rowB = bj * 128;
        const short* baseA = featb + (size_t)rowA * D_FEAT;
        const short* baseB = featb + (size_t)rowB * D_FEAT;

        // per-thread staging source: chunk cid = it*256+tid; pos = cid&3 holds
        // data chunk (pos ^ (r&3))  [pre-swizzled source, linear LDS dest]
        int r0 = tid >> 2, cpos0 = tid & 3;
        int r1 = (256 + tid) >> 2, cpos1 = (256 + tid) & 3;
        int src0 = r0 * D_FEAT + (cpos0 ^ (r0 & 3)) * 8;
        int src1 = r1 * D_FEAT + (cpos1 ^ (r1 & 3)) * 8;
        int ldsoff0 = (wid * 64) * 8;           // shorts, wave-uniform
        int ldsoff1 = (256 + wid * 64) * 8;

        for (int k0 = 0; k0 < D_FEAT; k0 += 32) {
            gload_lds16(baseA + src0 + k0, &As[ldsoff0]);
            gload_lds16(baseB + src0 + k0, &Bs[ldsoff0]);
            gload_lds16(baseA + src1 + k0, &As[ldsoff1]);
            gload_lds16(baseB + src1 + k0, &Bs[ldsoff1]);
            __syncthreads();

            bf16x8 afr[4], bfr[4];
            #pragma unroll
            for (int mi = 0; mi < 4; ++mi)
                afr[mi] = *(const bf16x8*)(&As[(wr * 64 + mi * 16 + fr) * 32 + sw]);
            #pragma unroll
            for (int ni = 0; ni < 4; ++ni)
                bfr[ni] = *(const bf16x8*)(&Bs[(wc * 64 + ni * 16 + fr) * 32 + sw]);

            #pragma unroll
            for (int mi = 0; mi < 4; ++mi)
                #pragma unroll
                for (int ni = 0; ni < 4; ++ni)
                    acc[mi][ni] = __builtin_amdgcn_mfma_f32_16x16x32_bf16(afr[mi], bfr[ni], acc[mi][ni], 0, 0, 0);
            __syncthreads();
        }

        // epilogue: hinge over strict lower triangle (row > col)
        float partial = 0.f;
        int rq = lane >> 4;
        #pragma unroll
        for (int mi = 0; mi < 4; ++mi) {
            #pragma unroll
            for (int ni = 0; ni < 4; ++ni) {
                #pragma unroll
                for (int rr = 0; rr < 4; ++rr) {
                    int grow = rowA + wr * 64 + mi * 16 + rq * 4 + rr;
                    int gcol = rowB + wc * 64 + ni * 16 + fr;
                    if (grow > gcol) {
                        float c = acc[mi][ni][rr] / fmaxf(norms[grow] * norms[gcol], 1e-8f);
                        partial += fmaxf(c, 0.f);
                    }
                }
            }
        }
        #pragma unroll
        for (int off = 1; off < 64; off <<= 1) partial += __shfl_xor(partial, off);
        if (lane == 0) red[wid] = partial;
        __syncthreads();
        if (tid == 0) atomicAdd(accums + 1, red[0] + red[1] + red[2] + red[3]);
    } else {
        // ---- cross entropy: one block per row ----
        int row = blockIdx.x - NBLK_GRAM;
        const float* rp = logits + (size_t)row * N_CLASSES;
        const float4* rp4 = (const float4*)rp;
        float m = -3.4e38f, s = 0.f;
        for (int j = tid; j < N_CLASSES / 4; j += 256) {
            float4 v = rp4[j];
            float vm = fmaxf(fmaxf(v.x, v.y), fmaxf(v.z, v.w));
            if (vm > m) { s *= __expf(m - vm); m = vm; }
            s += __expf(v.x - m) + __expf(v.y - m) + __expf(v.z - m) + __expf(v.w - m);
        }
        #pragma unroll
        for (int off = 1; off < 64; off <<= 1) {
            float om = __shfl_xor(m, off);
            float os = __shfl_xor(s, off);
            float M = fmaxf(m, om);
            s = s * __expf(m - M) + os * __expf(om - M);
            m = M;
        }
        if (lane == 0) { red[wid] = m; red[4 + wid] = s; }
        __syncthreads();
        if (tid == 0) {
            float M = fmaxf(fmaxf(red[0], red[1]), fmaxf(red[2], red[3]));
            float S = red[4] * __expf(red[0] - M) + red[5] * __expf(red[1] - M)
                    + red[6] * __expf(red[2] - M) + red[7] * __expf(red[3] - M);
            float lse = M + logf(S);
            atomicAdd(accums, lse - rp[labels[row]]);
        }
    }
}

// ---------------- finalize ----------------
__global__ void finalize_kernel(const float* __restrict__ accums, float* __restrict__ out) {
    float ce = accums[0] / (float)N_ROWS;
    float contrastive = 2.f * accums[1] / ((float)N_ROWS * (float)(N_ROWS - 1));
    out[0] = ce + 0.1f * contrastive;
}

extern "C" void kernel_launch(void* const* d_in, const int* in_sizes, int n_in,
                              void* d_out, int out_size, void* d_ws, size_t ws_size,
                              hipStream_t stream) {
    const float* logits = (const float*)d_in[0];
    const int*   labels = (const int*)d_in[1];
    const float* feat   = (const float*)d_in[2];
    float* out = (float*)d_out;

    float* accums = (float*)d_ws;                         // [0]=ce, [1]=hinge
    float* norms  = (float*)((char*)d_ws + 256);          // 4096 f32
    short* featb  = (short*)((char*)d_ws + 65536);        // 4096x1024 bf16 (8 MB)

    prep_kernel<<<N_ROWS, 256, 0, stream>>>(feat, featb, norms, accums);
    fused_kernel<<<NBLK_GRAM + N_ROWS, 256, 0, stream>>>(logits, labels, featb, norms, accums);
    finalize_kernel<<<1, 1, 0, stream>>>(accums, out);
}